// Round 3
// baseline (936.867 us; speedup 1.0000x reference)
//
#include <hip/hip_runtime.h>
#include <hip/hip_fp16.h>

constexpr int N = 4;
constexpr int C = 64;
constexpr int H = 256;
constexpr int W = 448;
constexpr int HW = H * W;

constexpr int TS = 16;                    // tile side
constexpr int TX = W / TS;                // 28 tiles in x
constexpr int TY = H / TS;                // 16 tiles in y
constexpr int TILES_PER_B = TX * TY;      // 448
constexpr int TILES = N * TILES_PER_B;    // 1792
constexpr int CAP = 1024;                 // records per tile (expected ~290)
constexpr int OVCAP = 8192;               // global overflow records

// ws layout (bytes):
//   scr2   : N*HW*64 f16  = 58,720,256
//   recs   : TILES*CAP*16 = 29,360,128
//   cnt    : TILES*4      = 7,168
//   ov_cnt : 4  (+12 pad)
//   ov_tile: OVCAP*4
//   ov_rec : OVCAP*16
constexpr size_t SCR2_BYTES = (size_t)N * HW * C * 2;
constexpr size_t RECS_BYTES = (size_t)TILES * CAP * 16;
constexpr size_t CNT_OFF    = SCR2_BYTES + RECS_BYTES;
constexpr size_t OVCNT_OFF  = CNT_OFF + (size_t)TILES * 4;
constexpr size_t OVTILE_OFF = OVCNT_OFF + 16;
constexpr size_t OVREC_OFF  = OVTILE_OFF + (size_t)OVCAP * 4;
constexpr size_t WS_NEED    = OVREC_OFF + (size_t)OVCAP * 16;

// ---------------- Phase 0: NCHW fp32 -> NHWC f16, premultiplied by m ---------
__global__ __launch_bounds__(256) void transpose_premul(
    const float* __restrict__ input,
    const float* __restrict__ metric,
    __half2* __restrict__ scr2)
{
    __shared__ float s[64][65];
    __shared__ float s_m[64];

    const int tid = threadIdx.x;
    const int p0 = blockIdx.x * 64;       // HW % 64 == 0: no batch straddle
    const int b  = p0 / HW;
    const int pb = p0 - b * HW;

    if (tid < 64) s_m[tid] = __expf(metric[b * HW + pb + tid]);

    const int pix = tid & 63;
    for (int c = tid >> 6; c < C; c += 4)
        s[pix][c] = input[((size_t)(b * C + c)) * HW + pb + pix];
    __syncthreads();

    const int cp = tid & 31;              // channel pair
    for (int i = 0; i < 8; ++i) {
        const int q = i * 8 + (tid >> 5); // pixel within block
        const float m = s_m[q];
        scr2[((size_t)(b * HW + pb + q)) * 32 + cp] =
            __floats2half2_rn(s[q][2 * cp] * m, s[q][2 * cp + 1] * m);
    }
}

// ---------------- Phase A: bin source pixels into target tiles ---------------
__global__ __launch_bounds__(256) void bin_kernel(
    const float* __restrict__ flow,
    const float* __restrict__ metric,
    float4* __restrict__ recs,
    int* __restrict__ cnt,
    int* __restrict__ ov_cnt,
    int* __restrict__ ov_tile,
    float4* __restrict__ ov_rec)
{
    const int idx = blockIdx.x * blockDim.x + threadIdx.x;
    if (idx >= N * HW) return;
    const int b = idx / HW;
    const int p = idx - b * HW;
    const int y = p / W;
    const int x = p - y * W;

    const float fx = (float)x + flow[(b * 2 + 0) * HW + p];
    const float fy = (float)y + flow[(b * 2 + 1) * HW + p];
    const float m  = __expf(metric[b * HW + p]);

    const int x0 = (int)floorf(fx);
    const int y0 = (int)floorf(fy);

    const int cx_lo = max(x0, 0),  cx_hi = min(x0 + 1, W - 1);
    const int cy_lo = max(y0, 0),  cy_hi = min(y0 + 1, H - 1);
    if (cx_lo > cx_hi || cy_lo > cy_hi) return;   // fully out of frame

    const float4 rec = make_float4(__int_as_float(p), fx, fy, m);

    for (int ty = cy_lo >> 4; ty <= (cy_hi >> 4); ++ty)
        for (int tx = cx_lo >> 4; tx <= (cx_hi >> 4); ++tx) {
            const int tile = b * TILES_PER_B + ty * TX + tx;
            const int pos = atomicAdd(&cnt[tile], 1);
            if (pos < CAP) {
                recs[(size_t)tile * CAP + pos] = rec;
            } else {
                const int o = atomicAdd(ov_cnt, 1);
                if (o < OVCAP) { ov_tile[o] = tile; ov_rec[o] = rec; }
            }
        }
}

// ---------------- Phase B: per-tile gather + normalize + write ---------------
__device__ __forceinline__ void process_record(
    const float4 rec, const __half2* __restrict__ scr2,
    int b, int x0t, int y0t, int hl,
    float (* __restrict__ s_acc)[65], float* __restrict__ s_norm)
{
    const int   src = __float_as_int(rec.x);
    const float fx = rec.y, fy = rec.z, m = rec.w;

    const float x0f = floorf(fx), y0f = floorf(fy);
    const int x0 = (int)x0f, y0 = (int)y0f;
    const float wx1 = fx - x0f, wx0 = 1.0f - wx1;
    const float wy1 = fy - y0f, wy0 = 1.0f - wy1;

    const float2 v = __half22float2(scr2[((size_t)(b * HW + src)) * 32 + hl]);

#pragma unroll
    for (int k = 0; k < 4; ++k) {
        const int xx = x0 + (k & 1);
        const int yy = y0 + (k >> 1);
        const int lx = xx - x0t;
        const int ly = yy - y0t;
        if (lx >= 0 && lx < TS && ly >= 0 && ly < TS) {
            const float w = ((k & 1) ? wx1 : wx0) * ((k >> 1) ? wy1 : wy0);
            const int pix = ly * TS + lx;
            atomicAdd(&s_acc[pix][2 * hl],     v.x * w);
            atomicAdd(&s_acc[pix][2 * hl + 1], v.y * w);
            if (hl == 0) atomicAdd(&s_norm[pix], m * w);
        }
    }
}

__global__ __launch_bounds__(256) void gather_kernel(
    const __half2* __restrict__ scr2,
    const float4* __restrict__ recs,
    const int* __restrict__ cnt,
    const int* __restrict__ ov_cnt,
    const int* __restrict__ ov_tile,
    const float4* __restrict__ ov_rec,
    float* __restrict__ out)
{
    __shared__ float s_acc[TS * TS][65];
    __shared__ float s_norm[TS * TS];

    const int tid  = threadIdx.x;
    const int tile = blockIdx.x;
    const int b    = tile / TILES_PER_B;
    const int tt   = tile - b * TILES_PER_B;
    const int y0t  = (tt / TX) * TS;
    const int x0t  = (tt - (tt / TX) * TX) * TS;

    // zero accumulators
    for (int e = tid; e < TS * TS * 65; e += 256)
        ((float*)s_acc)[e] = 0.0f;
    if (tid < TS * TS) s_norm[tid] = 0.0f;
    __syncthreads();

    const int wave = tid >> 6;
    const int lane = tid & 63;
    const int half = lane >> 5;
    const int hl   = lane & 31;

    const int nrec = min(cnt[tile], CAP);
    const float4* tr = recs + (size_t)tile * CAP;

    for (int r0 = wave * 2; r0 < nrec; r0 += 8) {
        const int r = r0 + half;
        if (r < nrec)
            process_record(tr[r], scr2, b, x0t, y0t, hl, s_acc, s_norm);
    }

    const int ovn = min(*ov_cnt, OVCAP);
    for (int r0 = wave * 2; r0 < ovn; r0 += 8) {
        const int r = r0 + half;
        if (r < ovn && ov_tile[r] == tile)
            process_record(ov_rec[r], scr2, b, x0t, y0t, hl, s_acc, s_norm);
    }
    __syncthreads();

    if (tid < TS * TS) {
        const float n = s_norm[tid];
        s_norm[tid] = (n == 0.0f) ? 1.0f : (1.0f / n);
    }
    __syncthreads();

    // write NCHW: iteration i = channel, lanes = pixels (16x 64B rows/wave pass)
    for (int i = 0; i < C; ++i) {
        const int pix = tid;
        const int ly = pix >> 4, lx = pix & 15;
        out[((size_t)(b * C + i)) * HW + (y0t + ly) * W + x0t + lx] =
            s_acc[pix][i] * s_norm[pix];
    }
}

// ---------------- Fallback (R1 style, tiny ws) -------------------------------
__global__ void splat_kernel(const float* __restrict__ input,
                             const float* __restrict__ flow,
                             const float* __restrict__ metric,
                             float* __restrict__ out,
                             float* __restrict__ norm)
{
    int idx = blockIdx.x * blockDim.x + threadIdx.x;
    if (idx >= N * HW) return;
    int b = idx / HW;
    int p = idx - b * HW;
    int y = p / W;
    int x = p - y * W;

    float fx = (float)x + flow[(b * 2 + 0) * HW + p];
    float fy = (float)y + flow[(b * 2 + 1) * HW + p];
    float m  = __expf(metric[b * HW + p]);

    float x0f = floorf(fx), y0f = floorf(fy);
    int x0 = (int)x0f, y0 = (int)y0f;
    int x1 = x0 + 1,   y1 = y0 + 1;
    float wx1 = fx - x0f, wx0 = 1.0f - wx1;
    float wy1 = fy - y0f, wy0 = 1.0f - wy1;

    bool vx0 = (x0 >= 0) & (x0 < W);
    bool vx1 = (x1 >= 0) & (x1 < W);
    bool vy0 = (y0 >= 0) & (y0 < H);
    bool vy1 = (y1 >= 0) & (y1 < H);

    bool vNW = vx0 & vy0, vNE = vx1 & vy0, vSW = vx0 & vy1, vSE = vx1 & vy1;
    float wNW = wx0 * wy0, wNE = wx1 * wy0, wSW = wx0 * wy1, wSE = wx1 * wy1;
    int iNW = y0 * W + x0, iNE = y0 * W + x1, iSW = y1 * W + x0, iSE = y1 * W + x1;

    {
        float* nb = norm + b * HW;
        if (vNW) atomicAdd(nb + iNW, m * wNW);
        if (vNE) atomicAdd(nb + iNE, m * wNE);
        if (vSW) atomicAdd(nb + iSW, m * wSW);
        if (vSE) atomicAdd(nb + iSE, m * wSE);
    }

    const float* ib = input + (size_t)b * C * HW + p;
    float* ob = out + (size_t)b * C * HW;
#pragma unroll 4
    for (int c = 0; c < C; ++c) {
        float v = ib[(size_t)c * HW] * m;
        float* oc = ob + (size_t)c * HW;
        if (vNW) atomicAdd(oc + iNW, v * wNW);
        if (vNE) atomicAdd(oc + iNE, v * wNE);
        if (vSW) atomicAdd(oc + iSW, v * wSW);
        if (vSE) atomicAdd(oc + iSE, v * wSE);
    }
}

__global__ void norm_kernel(float* __restrict__ out,
                            const float* __restrict__ norm)
{
    int idx = blockIdx.x * blockDim.x + threadIdx.x;
    int total = N * C * HW / 4;
    if (idx >= total) return;
    int pixq = idx % (HW / 4);
    int bc   = idx / (HW / 4);
    int b    = bc / C;

    const float4* np4 = (const float4*)(norm + (size_t)b * HW);
    float4 n = np4[pixq];
    n.x = (n.x == 0.0f) ? 1.0f : n.x;
    n.y = (n.y == 0.0f) ? 1.0f : n.y;
    n.z = (n.z == 0.0f) ? 1.0f : n.z;
    n.w = (n.w == 0.0f) ? 1.0f : n.w;

    float4* o4 = (float4*)out;
    float4 v = o4[idx];
    v.x /= n.x; v.y /= n.y; v.z /= n.z; v.w /= n.w;
    o4[idx] = v;
}

// ============================================================================
extern "C" void kernel_launch(void* const* d_in, const int* in_sizes, int n_in,
                              void* d_out, int out_size, void* d_ws, size_t ws_size,
                              hipStream_t stream)
{
    const float* input  = (const float*)d_in[0];   // (4,64,256,448)
    const float* flow   = (const float*)d_in[1];   // (4,2,256,448)
    const float* metric = (const float*)d_in[2];   // (4,1,256,448)
    float* out = (float*)d_out;

    if (ws_size >= WS_NEED) {
        char* ws = (char*)d_ws;
        __half2* scr2   = (__half2*)ws;
        float4*  recs   = (float4*)(ws + SCR2_BYTES);
        int*     cnt    = (int*)(ws + CNT_OFF);
        int*     ov_cnt = (int*)(ws + OVCNT_OFF);
        int*     ov_tile= (int*)(ws + OVTILE_OFF);
        float4*  ov_rec = (float4*)(ws + OVREC_OFF);

        // zero counters (cnt + ov_cnt region is contiguous)
        hipMemsetAsync(cnt, 0, (size_t)TILES * 4 + 16, stream);

        transpose_premul<<<N * HW / 64, 256, 0, stream>>>(input, metric, scr2);
        bin_kernel<<<(N * HW + 255) / 256, 256, 0, stream>>>(
            flow, metric, recs, cnt, ov_cnt, ov_tile, ov_rec);
        gather_kernel<<<TILES, 256, 0, stream>>>(
            scr2, recs, cnt, ov_cnt, ov_tile, ov_rec, out);
    } else {
        float* norm = (float*)d_ws;
        hipMemsetAsync(out,  0, (size_t)N * C * HW * sizeof(float), stream);
        hipMemsetAsync(norm, 0, (size_t)N * HW * sizeof(float), stream);
        splat_kernel<<<(N * HW + 255) / 256, 256, 0, stream>>>(input, flow, metric, out, norm);
        int total = N * C * HW / 4;
        norm_kernel<<<(total + 255) / 256, 256, 0, stream>>>(out, norm);
    }
}

// Round 4
// 879.952 us; speedup vs baseline: 1.0647x; 1.0647x over previous
//
#include <hip/hip_runtime.h>
#include <hip/hip_fp16.h>

constexpr int N = 4;
constexpr int C = 64;
constexpr int H = 256;
constexpr int W = 448;
constexpr int HW = H * W;

constexpr int TSX = 16;                   // tile width
constexpr int TSY = 8;                    // tile height
constexpr int PIX = TSX * TSY;            // 128 pixels per tile
constexpr int TXn = W / TSX;              // 28
constexpr int TYn = H / TSY;              // 32
constexpr int TILES_PER_B = TXn * TYn;    // 896
constexpr int TILES = N * TILES_PER_B;    // 3584
constexpr int CAP = 512;                  // records per tile (expected ~153)
constexpr int OVCAP = 8192;

// ws layout (bytes)
constexpr size_t SCR2_BYTES = (size_t)N * HW * C * 2;        // 58.7 MB
constexpr size_t RECS_BYTES = (size_t)TILES * CAP * 16;      // 29.4 MB
constexpr size_t CNT_OFF    = SCR2_BYTES + RECS_BYTES;
constexpr size_t OVCNT_OFF  = CNT_OFF + (size_t)TILES * 4;
constexpr size_t OVTILE_OFF = OVCNT_OFF + 16;
constexpr size_t OVREC_OFF  = OVTILE_OFF + (size_t)OVCAP * 4;
constexpr size_t WS_NEED    = OVREC_OFF + (size_t)OVCAP * 16;

// ---------------- Phase 0: NCHW fp32 -> NHWC f16, premultiplied by m ---------
__global__ __launch_bounds__(256) void transpose_premul(
    const float* __restrict__ input,
    const float* __restrict__ metric,
    __half2* __restrict__ scr2)
{
    __shared__ float s[128][65];     // 33.3 KB
    __shared__ float s_m[128];

    const int tid = threadIdx.x;
    const int p0 = blockIdx.x * 128;          // HW % 128 == 0: no batch straddle
    const int b  = p0 / HW;
    const int pb = p0 - b * HW;

    if (tid < 128) s_m[tid] = __expf(metric[b * HW + pb + tid]);

    // coalesced reads: 128 consecutive pixels (512B) per channel row
    const int pix = tid & 127;
    for (int c = tid >> 7; c < C; c += 2)
        s[pix][c] = input[((size_t)(b * C + c)) * HW + pb + pix];
    __syncthreads();

    // coalesced writes: lanes = channel pairs, 8 pixels per pass (1KB/256thr)
    const int cp = tid & 31;
    const int q0 = tid >> 5;
    for (int i = 0; i < 16; ++i) {
        const int q = i * 8 + q0;
        const float m = s_m[q];
        scr2[((size_t)(b * HW + pb + q)) * 32 + cp] =
            __floats2half2_rn(s[q][2 * cp] * m, s[q][2 * cp + 1] * m);
    }
}

// ---------------- Phase A: bin source pixels into target tiles ---------------
__global__ __launch_bounds__(256) void bin_kernel(
    const float* __restrict__ flow,
    const float* __restrict__ metric,
    float4* __restrict__ recs,
    int* __restrict__ cnt,
    int* __restrict__ ov_cnt,
    int* __restrict__ ov_tile,
    float4* __restrict__ ov_rec)
{
    const int idx = blockIdx.x * blockDim.x + threadIdx.x;
    if (idx >= N * HW) return;
    const int b = idx / HW;
    const int p = idx - b * HW;
    const int y = p / W;
    const int x = p - y * W;

    const float fx = (float)x + flow[(b * 2 + 0) * HW + p];
    const float fy = (float)y + flow[(b * 2 + 1) * HW + p];
    const float m  = __expf(metric[b * HW + p]);

    const int x0 = (int)floorf(fx);
    const int y0 = (int)floorf(fy);

    const int cx_lo = max(x0, 0),  cx_hi = min(x0 + 1, W - 1);
    const int cy_lo = max(y0, 0),  cy_hi = min(y0 + 1, H - 1);
    if (cx_lo > cx_hi || cy_lo > cy_hi) return;

    const float4 rec = make_float4(__int_as_float(p), fx, fy, m);

    for (int ty = cy_lo >> 3; ty <= (cy_hi >> 3); ++ty)
        for (int tx = cx_lo >> 4; tx <= (cx_hi >> 4); ++tx) {
            const int tile = b * TILES_PER_B + ty * TXn + tx;
            const int pos = atomicAdd(&cnt[tile], 1);
            if (pos < CAP) {
                recs[(size_t)tile * CAP + pos] = rec;
            } else {
                const int o = atomicAdd(ov_cnt, 1);
                if (o < OVCAP) { ov_tile[o] = tile; ov_rec[o] = rec; }
            }
        }
}

// ---------------- Phase B: per-tile gather + normalize + write ---------------
__device__ __forceinline__ void process_record(
    const float4 rec, const float2 v,
    int x0t, int y0t, int hl,
    float (* __restrict__ s_acc)[65], float* __restrict__ s_norm)
{
    const float fx = rec.y, fy = rec.z, m = rec.w;

    const float x0f = floorf(fx), y0f = floorf(fy);
    const int x0 = (int)x0f, y0 = (int)y0f;
    const float wx1 = fx - x0f, wx0 = 1.0f - wx1;
    const float wy1 = fy - y0f, wy0 = 1.0f - wy1;

#pragma unroll
    for (int k = 0; k < 4; ++k) {
        const int lx = x0 + (k & 1) - x0t;
        const int ly = y0 + (k >> 1) - y0t;
        if (lx >= 0 && lx < TSX && ly >= 0 && ly < TSY) {
            const float w = ((k & 1) ? wx1 : wx0) * ((k >> 1) ? wy1 : wy0);
            const int pix = ly * TSX + lx;
            atomicAdd(&s_acc[pix][2 * hl],     v.x * w);
            atomicAdd(&s_acc[pix][2 * hl + 1], v.y * w);
            if (hl == 0) atomicAdd(&s_norm[pix], m * w);
        }
    }
}

__global__ __launch_bounds__(256) void gather_kernel(
    const __half2* __restrict__ scr2,
    const float4* __restrict__ recs,
    const int* __restrict__ cnt,
    const int* __restrict__ ov_cnt,
    const int* __restrict__ ov_tile,
    const float4* __restrict__ ov_rec,
    float* __restrict__ out)
{
    __shared__ float s_acc[PIX][65];          // 33.3 KB
    __shared__ float s_norm[PIX];

    const int tid  = threadIdx.x;
    const int tile = blockIdx.x;
    const int b    = tile / TILES_PER_B;
    const int tt   = tile - b * TILES_PER_B;
    const int y0t  = (tt / TXn) * TSY;
    const int x0t  = (tt - (tt / TXn) * TXn) * TSX;

    for (int e = tid; e < PIX * 65; e += 256)
        ((float*)s_acc)[e] = 0.0f;
    if (tid < PIX) s_norm[tid] = 0.0f;
    __syncthreads();

    const int team = tid >> 5;        // 0..7 (32-lane record teams)
    const int hl   = tid & 31;        // channel pair

    const int nrec = min(cnt[tile], CAP);
    const float4* tr = recs + (size_t)tile * CAP;
    const __half2* sbase = scr2 + (size_t)b * HW * 32 + hl;

    // 4-deep record pipeline per team: 4 independent header loads, then
    // 4 independent 128B strip loads, then LDS accumulation.
    for (int r0 = team * 4; r0 < nrec; r0 += 32) {
        float4 rc[4];
        float2 v[4];
#pragma unroll
        for (int u = 0; u < 4; ++u)
            if (r0 + u < nrec) rc[u] = tr[r0 + u];
#pragma unroll
        for (int u = 0; u < 4; ++u)
            if (r0 + u < nrec)
                v[u] = __half22float2(sbase[(size_t)__float_as_int(rc[u].x) * 32]);
#pragma unroll
        for (int u = 0; u < 4; ++u)
            if (r0 + u < nrec)
                process_record(rc[u], v[u], x0t, y0t, hl, s_acc, s_norm);
    }

    // overflow (normally empty)
    const int ovn = min(*ov_cnt, OVCAP);
    for (int r = team; r < ovn; r += 8) {
        if (ov_tile[r] == tile) {
            const float4 rc = ov_rec[r];
            const float2 v = __half22float2(sbase[(size_t)__float_as_int(rc.x) * 32]);
            process_record(rc, v, x0t, y0t, hl, s_acc, s_norm);
        }
    }
    __syncthreads();

    if (tid < PIX) {
        const float n = s_norm[tid];
        s_norm[tid] = (n == 0.0f) ? 1.0f : (1.0f / n);
    }
    __syncthreads();

    // write NCHW: lanes = consecutive pixels within tile rows (64B segments)
    for (int i = 0; i < PIX * C / 256; ++i) {
        const int e = i * 256 + tid;
        const int c = e >> 7;                 // 0..63
        const int pix = e & 127;
        const int ly = pix >> 4, lx = pix & 15;
        out[((size_t)(b * C + c)) * HW + (y0t + ly) * W + x0t + lx] =
            s_acc[pix][c] * s_norm[pix];
    }
}

// ---------------- Fallback (tiny ws) ----------------------------------------
__global__ void splat_kernel(const float* __restrict__ input,
                             const float* __restrict__ flow,
                             const float* __restrict__ metric,
                             float* __restrict__ out,
                             float* __restrict__ norm)
{
    int idx = blockIdx.x * blockDim.x + threadIdx.x;
    if (idx >= N * HW) return;
    int b = idx / HW;
    int p = idx - b * HW;
    int y = p / W;
    int x = p - y * W;

    float fx = (float)x + flow[(b * 2 + 0) * HW + p];
    float fy = (float)y + flow[(b * 2 + 1) * HW + p];
    float m  = __expf(metric[b * HW + p]);

    float x0f = floorf(fx), y0f = floorf(fy);
    int x0 = (int)x0f, y0 = (int)y0f;
    int x1 = x0 + 1,   y1 = y0 + 1;
    float wx1 = fx - x0f, wx0 = 1.0f - wx1;
    float wy1 = fy - y0f, wy0 = 1.0f - wy1;

    bool vx0 = (x0 >= 0) & (x0 < W);
    bool vx1 = (x1 >= 0) & (x1 < W);
    bool vy0 = (y0 >= 0) & (y0 < H);
    bool vy1 = (y1 >= 0) & (y1 < H);

    bool vNW = vx0 & vy0, vNE = vx1 & vy0, vSW = vx0 & vy1, vSE = vx1 & vy1;
    float wNW = wx0 * wy0, wNE = wx1 * wy0, wSW = wx0 * wy1, wSE = wx1 * wy1;
    int iNW = y0 * W + x0, iNE = y0 * W + x1, iSW = y1 * W + x0, iSE = y1 * W + x1;

    {
        float* nb = norm + b * HW;
        if (vNW) atomicAdd(nb + iNW, m * wNW);
        if (vNE) atomicAdd(nb + iNE, m * wNE);
        if (vSW) atomicAdd(nb + iSW, m * wSW);
        if (vSE) atomicAdd(nb + iSE, m * wSE);
    }

    const float* ib = input + (size_t)b * C * HW + p;
    float* ob = out + (size_t)b * C * HW;
#pragma unroll 4
    for (int c = 0; c < C; ++c) {
        float v = ib[(size_t)c * HW] * m;
        float* oc = ob + (size_t)c * HW;
        if (vNW) atomicAdd(oc + iNW, v * wNW);
        if (vNE) atomicAdd(oc + iNE, v * wNE);
        if (vSW) atomicAdd(oc + iSW, v * wSW);
        if (vSE) atomicAdd(oc + iSE, v * wSE);
    }
}

__global__ void norm_kernel(float* __restrict__ out,
                            const float* __restrict__ norm)
{
    int idx = blockIdx.x * blockDim.x + threadIdx.x;
    int total = N * C * HW / 4;
    if (idx >= total) return;
    int pixq = idx % (HW / 4);
    int bc   = idx / (HW / 4);
    int b    = bc / C;

    const float4* np4 = (const float4*)(norm + (size_t)b * HW);
    float4 n = np4[pixq];
    n.x = (n.x == 0.0f) ? 1.0f : n.x;
    n.y = (n.y == 0.0f) ? 1.0f : n.y;
    n.z = (n.z == 0.0f) ? 1.0f : n.z;
    n.w = (n.w == 0.0f) ? 1.0f : n.w;

    float4* o4 = (float4*)out;
    float4 v = o4[idx];
    v.x /= n.x; v.y /= n.y; v.z /= n.z; v.w /= n.w;
    o4[idx] = v;
}

// ============================================================================
extern "C" void kernel_launch(void* const* d_in, const int* in_sizes, int n_in,
                              void* d_out, int out_size, void* d_ws, size_t ws_size,
                              hipStream_t stream)
{
    const float* input  = (const float*)d_in[0];
    const float* flow   = (const float*)d_in[1];
    const float* metric = (const float*)d_in[2];
    float* out = (float*)d_out;

    if (ws_size >= WS_NEED) {
        char* ws = (char*)d_ws;
        __half2* scr2   = (__half2*)ws;
        float4*  recs   = (float4*)(ws + SCR2_BYTES);
        int*     cnt    = (int*)(ws + CNT_OFF);
        int*     ov_cnt = (int*)(ws + OVCNT_OFF);
        int*     ov_tile= (int*)(ws + OVTILE_OFF);
        float4*  ov_rec = (float4*)(ws + OVREC_OFF);

        hipMemsetAsync(cnt, 0, (size_t)TILES * 4 + 16, stream);

        transpose_premul<<<N * HW / 128, 256, 0, stream>>>(input, metric, scr2);
        bin_kernel<<<(N * HW + 255) / 256, 256, 0, stream>>>(
            flow, metric, recs, cnt, ov_cnt, ov_tile, ov_rec);
        gather_kernel<<<TILES, 256, 0, stream>>>(
            scr2, recs, cnt, ov_cnt, ov_tile, ov_rec, out);
    } else {
        float* norm = (float*)d_ws;
        hipMemsetAsync(out,  0, (size_t)N * C * HW * sizeof(float), stream);
        hipMemsetAsync(norm, 0, (size_t)N * HW * sizeof(float), stream);
        splat_kernel<<<(N * HW + 255) / 256, 256, 0, stream>>>(input, flow, metric, out, norm);
        int total = N * C * HW / 4;
        norm_kernel<<<(total + 255) / 256, 256, 0, stream>>>(out, norm);
    }
}